// Round 2
// baseline (178.425 us; speedup 1.0000x reference)
//
#include <hip/hip_runtime.h>
#include <hip/hip_bf16.h>

typedef __bf16 bf16;
typedef __attribute__((ext_vector_type(8))) __bf16 bf16x8;
typedef __attribute__((ext_vector_type(4))) float f32x4;
typedef __attribute__((ext_vector_type(4))) int i32x4;

#define CH 192
#define MAT (CH * CH)            // 36864
#define NF 145                   // canonical frequencies of 17x17 grid (conj symmetry)
#define FSTRIDE (2 * MAT)        // Re+Im per freq
#define NELEM (CH * CH * 9)      // 331776
#define XSCALE 9.765625e-4f      // 2^-10, exact; sigma = 1024*(s3/289)^(1/16)
#define W17 0.36959913571644626f // 2*pi/17

// ---------------------------------------------------------------------------
// sigma = ||G^3(K)||_F^(1/8) via 17x17 spectral sampling (exact Parseval).
// ROUND-7 CHANGE: per-frequency fusion. The pipeline X_f -> H1_f -> H2_f ->
// ||H3_f||^2 couples across frequencies only via the final scalar sum, and
// one frequency's 192x192 complex bf16 matrix = 147 KB fits in LDS (160 KB).
// k_g3: one block per freq runs all 3 gram rounds with intermediates in LDS
// (two 192x200 slabs Re/Im, 153.6 KB). 5 dispatches -> 3; bufH eliminated
// (-86 MB inter-round HBM/L3 traffic); 2 launch gaps removed.
// Lessons pinned from rounds 1-6:
//  - r4: runtime trip counts spill v[] to scratch. Staging FULLY UNROLLED
//    with compile-time indices.
//  - r6: spinner-block fusion of the scale +40 us. k_scale stays separate.
//    (k_g3 fusion is barrier-free across blocks: no grid sync needed.)
//  - r7: MFMA-based DFT regressed (scattered stores). VALU DFT + LDS twiddle.
//  - Strides: 16-B aligned b128 needs stride%8==0 (bf16). 200 elem = 400 B:
//    frag-read banks (ml*4 + h*4) mod 32 -> uniform 8-group spread, ~min.
// XCD locality: k_g3 block bid=f lands on XCD f%8 = the XCD whose k_dft
// blocks (bid&7 == f%8) wrote X_f -> staging reads are same-XCD L2 hits.
// ws layout: [0] float s3; [256] bufX bf16 [f][2][a][o] (21.4 MB).
// ---------------------------------------------------------------------------

// X[f][part][a*CH+o] = DFT_17x17(K[o][a])(w_f) * 2^-10.
// Thread owns p0..p0+7 (8 consecutive o, one a); kv in VGPRs across 5 freqs.
__global__ void k_dft(const float* __restrict__ K, bf16* __restrict__ X,
                      float* __restrict__ s3) {
    __shared__ float twc[17], tws[17];
    int bid = blockIdx.x;                 // 8 * 4 * 18 = 576
    int xcd = bid & 7;
    int r = bid >> 3;
    int g = r / 18, chunk = r % 18;
    int t = threadIdx.x;
    if (bid == 0 && t == 0) *s3 = 0.0f;   // stream-ordered: done before k_g3
    if (t < 17) {
        float s, c;
        __sincosf(-W17 * (float)t, &s, &c);
        twc[t] = c; tws[t] = s;
    }
    int p0 = chunk * 2048 + t * 8;        // p = a*CH + o; 8-run stays in one a-row
    int a = p0 / CH, o0 = p0 % CH;
    float kv[8][9];
#pragma unroll
    for (int j = 0; j < 8; ++j) {
        const float* src = K + ((size_t)(o0 + j) * CH + a) * 9;
#pragma unroll
        for (int i = 0; i < 9; ++i) kv[j][i] = src[i];
    }
    __syncthreads();
#pragma unroll
    for (int u = 0; u < 5; ++u) {
        int f = xcd + 8 * (g * 5 + u);    // f % 8 == xcd; covers f < 160
        if (f >= NF) continue;            // uniform per block
        int fy, fx;
        if (f < 9) { fy = 0; fx = f; }
        else { int uu = f - 9; fy = 1 + uu / 17; fx = uu % 17; }
        float pyr = twc[fy], pyi = tws[fy];
        float pxr = twc[fx], pxi = tws[fx];
        int fx2 = 2 * fx; if (fx2 >= 17) fx2 -= 17;
        int fy2 = 2 * fy; if (fy2 >= 17) fy2 -= 17;
        float px2r = twc[fx2], px2i = tws[fx2];
        float py2r = twc[fy2], py2i = tws[fy2];
        bf16x8 vr, vi;
#pragma unroll
        for (int j = 0; j < 8; ++j) {
            // row sums s_y = kv[y][0] + kv[y][1]*px + kv[y][2]*px^2  (kv real)
            float s0r = kv[j][0] + kv[j][1] * pxr + kv[j][2] * px2r, s0i = kv[j][1] * pxi + kv[j][2] * px2i;
            float s1r = kv[j][3] + kv[j][4] * pxr + kv[j][5] * px2r, s1i = kv[j][4] * pxi + kv[j][5] * px2i;
            float s2r = kv[j][6] + kv[j][7] * pxr + kv[j][8] * px2r, s2i = kv[j][7] * pxi + kv[j][8] * px2i;
            float ar = s0r + pyr * s1r - pyi * s1i + py2r * s2r - py2i * s2i;
            float ai = s0i + pyr * s1i + pyi * s1r + py2r * s2i + py2i * s2r;
            vr[j] = (bf16)(ar * XSCALE);
            vi[j] = (bf16)(ai * XSCALE);
        }
        size_t base = (size_t)f * FSTRIDE + p0;
        *(i32x4*)(X + base)       = __builtin_bit_cast(i32x4, vr);
        *(i32x4*)(X + base + MAT) = __builtin_bit_cast(i32x4, vi);
    }
}

// ---------------------------------------------------------------------------
// k_g3: per-frequency fused triple gram. One block = one freq, 512 threads.
// LDS: Re slab [192][200] bf16 + Im slab [192][200] = 153600 B.
// 12 wave-tiles of 48x48 (3 Hermitian quadrants x 2x2): wave w owns
// tile1 (rb,cb1); waves 0-3 additionally own tile2 (rb, cb1+96) in q1,
// sharing A-row fragments. Round: MFMA from LDS -> barrier -> accum->bf16
// write-back (q1 also writes conj-transpose into (96,0)) -> barrier.
// ---------------------------------------------------------------------------
#define S3S 200                   // slab stride (bf16 elems); 400 B rows
#define SLAB3 (192 * S3S)         // 38400 elems per slab

__global__ __launch_bounds__(512, 2) void k_g3(const bf16* __restrict__ X,
                                               float* __restrict__ s3) {
    __shared__ __align__(16) bf16 lds[2 * SLAB3];   // Re, Im: 153600 B
    __shared__ float red[8];
    int f = blockIdx.x;                 // 145 blocks; bid%8 == f%8 (writer XCD)
    const bf16* Xf = X + (size_t)f * FSTRIDE;
    int tid = threadIdx.x;
    int lane = tid & 63, w = tid >> 6;
    int ml = lane & 15, kq = (lane >> 4) * 8;
    int rb  = (w >> 1) * 48;                        // {0,0,48,48,96,96,144,144}
    int cb1 = ((w & 1) | ((w >> 1) & 2)) * 48;      // {0,48,0,48,96,144,96,144}
    int cb2 = cb1 + 96;                             // q1 pair for w<4
    bool two = (w < 4);

    // ---- stage X_f -> LDS (fully unrolled, compile-time v[] indices) ----
    {
        i32x4 v[18];
#pragma unroll
        for (int s = 0; s < 2; ++s)
#pragma unroll
            for (int j = 0; j < 9; ++j) {
                int c = j * 512 + tid;              // 4608 16-B chunks per slab
                int rr = c / 24, cc = c % 24;
                v[s * 9 + j] = *(const i32x4*)(Xf + (s ? MAT : 0) + rr * CH + cc * 8);
            }
#pragma unroll
        for (int s = 0; s < 2; ++s)
#pragma unroll
            for (int j = 0; j < 9; ++j) {
                int c = j * 512 + tid;
                int rr = c / 24, cc = c % 24;
                *(i32x4*)&lds[s * SLAB3 + rr * S3S + cc * 8] = v[s * 9 + j];
            }
    }
    __syncthreads();

    f32x4 cr1[3][3], ci1[3][3], cr2[3][3], ci2[3][3];
#pragma unroll 1
    for (int round = 0; round < 3; ++round) {
#pragma unroll
        for (int i = 0; i < 3; ++i)
#pragma unroll
            for (int j = 0; j < 3; ++j) {
                cr1[i][j] = f32x4{0.f, 0.f, 0.f, 0.f};
                ci1[i][j] = f32x4{0.f, 0.f, 0.f, 0.f};
                cr2[i][j] = f32x4{0.f, 0.f, 0.f, 0.f};
                ci2[i][j] = f32x4{0.f, 0.f, 0.f, 0.f};
            }
#pragma unroll
        for (int ks = 0; ks < 192; ks += 32) {
            int ko = ks + kq;
            bf16x8 ar[3], ai[3], nai[3];
#pragma unroll
            for (int mt = 0; mt < 3; ++mt) {
                ar[mt] = *(const bf16x8*)&lds[(rb + mt * 16 + ml) * S3S + ko];
                ai[mt] = *(const bf16x8*)&lds[SLAB3 + (rb + mt * 16 + ml) * S3S + ko];
                i32x4 u = __builtin_bit_cast(i32x4, ai[mt]);
                u ^= 0x80008000;                    // negate 8 bf16
                nai[mt] = __builtin_bit_cast(bf16x8, u);
            }
#pragma unroll
            for (int nt = 0; nt < 3; ++nt) {
                bf16x8 br = *(const bf16x8*)&lds[(cb1 + nt * 16 + ml) * S3S + ko];
                bf16x8 bi = *(const bf16x8*)&lds[SLAB3 + (cb1 + nt * 16 + ml) * S3S + ko];
#pragma unroll
                for (int mt = 0; mt < 3; ++mt) {
                    cr1[mt][nt] = __builtin_amdgcn_mfma_f32_16x16x32_bf16(ar[mt],  br, cr1[mt][nt], 0, 0, 0);
                    cr1[mt][nt] = __builtin_amdgcn_mfma_f32_16x16x32_bf16(ai[mt],  bi, cr1[mt][nt], 0, 0, 0);
                    ci1[mt][nt] = __builtin_amdgcn_mfma_f32_16x16x32_bf16(ar[mt],  bi, ci1[mt][nt], 0, 0, 0);
                    ci1[mt][nt] = __builtin_amdgcn_mfma_f32_16x16x32_bf16(nai[mt], br, ci1[mt][nt], 0, 0, 0);
                }
                if (two) {
                    bf16x8 br2 = *(const bf16x8*)&lds[(cb2 + nt * 16 + ml) * S3S + ko];
                    bf16x8 bi2 = *(const bf16x8*)&lds[SLAB3 + (cb2 + nt * 16 + ml) * S3S + ko];
#pragma unroll
                    for (int mt = 0; mt < 3; ++mt) {
                        cr2[mt][nt] = __builtin_amdgcn_mfma_f32_16x16x32_bf16(ar[mt],  br2, cr2[mt][nt], 0, 0, 0);
                        cr2[mt][nt] = __builtin_amdgcn_mfma_f32_16x16x32_bf16(ai[mt],  bi2, cr2[mt][nt], 0, 0, 0);
                        ci2[mt][nt] = __builtin_amdgcn_mfma_f32_16x16x32_bf16(ar[mt],  bi2, ci2[mt][nt], 0, 0, 0);
                        ci2[mt][nt] = __builtin_amdgcn_mfma_f32_16x16x32_bf16(nai[mt], br2, ci2[mt][nt], 0, 0, 0);
                    }
                }
            }
        }
        if (round < 2) {
            __syncthreads();                        // all LDS reads done
            int lr = (lane >> 4) * 4;
#pragma unroll
            for (int mt = 0; mt < 3; ++mt)
#pragma unroll
                for (int nt = 0; nt < 3; ++nt)
#pragma unroll
                    for (int rr = 0; rr < 4; ++rr) {
                        int row = rb + mt * 16 + lr + rr;
                        int c1 = cb1 + nt * 16 + ml;
                        lds[row * S3S + c1]         = (bf16)cr1[mt][nt][rr];
                        lds[SLAB3 + row * S3S + c1] = (bf16)ci1[mt][nt][rr];
                        if (two) {
                            int c2 = cb2 + nt * 16 + ml;
                            float vr = cr2[mt][nt][rr], vi = ci2[mt][nt][rr];
                            lds[row * S3S + c2]         = (bf16)vr;
                            lds[SLAB3 + row * S3S + c2] = (bf16)vi;
                            // Hermitian reconstruction: H[c2][row] = conj
                            lds[c2 * S3S + row]         = (bf16)vr;
                            lds[SLAB3 + c2 * S3S + row] = (bf16)(-vi);
                        }
                    }
            __syncthreads();                        // writes visible to round+1
        }
    }

    // ---- norm of round-3 accums; q1 tiles weighted 2 (Hermitian pair) ----
    float loc = 0.f;
#pragma unroll
    for (int mt = 0; mt < 3; ++mt)
#pragma unroll
        for (int nt = 0; nt < 3; ++nt)
#pragma unroll
            for (int rr = 0; rr < 4; ++rr)
                loc += cr1[mt][nt][rr] * cr1[mt][nt][rr] + ci1[mt][nt][rr] * ci1[mt][nt][rr];
    if (two) {
        float l2 = 0.f;
#pragma unroll
        for (int mt = 0; mt < 3; ++mt)
#pragma unroll
            for (int nt = 0; nt < 3; ++nt)
#pragma unroll
                for (int rr = 0; rr < 4; ++rr)
                    l2 += cr2[mt][nt][rr] * cr2[mt][nt][rr] + ci2[mt][nt][rr] * ci2[mt][nt][rr];
        loc += 2.0f * l2;
    }
#pragma unroll
    for (int off = 32; off > 0; off >>= 1) loc += __shfl_down(loc, off, 64);
    if (lane == 0) red[w] = loc;
    __syncthreads();
    if (tid == 0) {
        float base = (f == 0) ? 1.0f : 2.0f;        // conj-pair weight over freqs
        atomicAdd(s3, base * (red[0] + red[1] + red[2] + red[3] +
                              red[4] + red[5] + red[6] + red[7]));
    }
}

// sigma = 1024 * (s3/289)^(1/16);  out = K / sigma
__global__ void k_scale(const float* __restrict__ K, float* __restrict__ out,
                        const float* __restrict__ s3) {
    float sig = 1024.0f * exp2f(log2f((*s3) * (1.0f / 289.0f)) * 0.0625f);
    float inv = 1.0f / sig;
    int i = (blockIdx.x * 256 + threadIdx.x) * 4;   // 324 blocks exact
    f32x4 v = *(const f32x4*)(K + i);
    v *= inv;
    *(f32x4*)(out + i) = v;
}

extern "C" void kernel_launch(void* const* d_in, const int* in_sizes, int n_in,
                              void* d_out, int out_size, void* d_ws, size_t ws_size,
                              hipStream_t stream) {
    const float* K = (const float*)d_in[0];
    float* out = (float*)d_out;
    char* ws = (char*)d_ws;
    float* s3 = (float*)ws;
    bf16* bufX = (bf16*)(ws + 256);

    k_dft<<<8 * 4 * 18, 256, 0, stream>>>(K, bufX, s3);       // X (21.4 MB)
    k_g3<<<NF, 512, 0, stream>>>(bufX, s3);                   // 3 gram rounds in LDS
    k_scale<<<NELEM / 1024, 256, 0, stream>>>(K, out, s3);    // out = K/sigma
}

// Round 3
// 172.545 us; speedup vs baseline: 1.0341x; 1.0341x over previous
//
#include <hip/hip_runtime.h>
#include <hip/hip_bf16.h>

typedef __bf16 bf16;
typedef __attribute__((ext_vector_type(8))) __bf16 bf16x8;
typedef __attribute__((ext_vector_type(4))) float f32x4;
typedef __attribute__((ext_vector_type(4))) int i32x4;

#define CH 192
#define MAT (CH * CH)            // 36864
#define NF 145                   // canonical frequencies of 17x17 grid (conj symmetry)
#define FSTRIDE (2 * MAT)        // Re+Im per freq
#define NELEM (CH * CH * 9)      // 331776
#define XSCALE 9.765625e-4f      // 2^-10, exact; sigma = 1024*(s3/289)^(1/16)
#define W17 0.36959913571644626f // 2*pi/17

// ---------------------------------------------------------------------------
// sigma = ||G^3(K)||_F^(1/8) via 17x17 spectral sampling (exact Parseval).
// ROUND-8 CHANGE (spill fix): round-7's fused k_g3 spilled its accumulators
// (VGPR_Count=128 < ~190 live; WRITE_SIZE=51MB of scratch on a kernel that
// writes one atomic; MfmaUtil 6%). Fixes:
//  - __launch_bounds__(512, 1): VGPR cap 512. Occupancy is LDS-bound at
//    1 block/CU (153.6 KB) either way, so registers are free.
//  - UNIFORM tiling: all 16 48x48 tiles (wave w = 48x96 strip; rb=(w>>1)*48,
//    cols (w&1)*96..+95). Drops the divergent Hermitian mirror (dead regs on
//    waves 4-7 + 1.42M conflict cycles of transposed scalar writes). Norm
//    weight = 1 per tile (full matrix), freq weight unchanged.
// Lessons pinned from rounds 1-7:
//  - r4: runtime trip counts spill v[] to scratch. Staging FULLY UNROLLED
//    with compile-time indices.
//  - r6: spinner-block fusion of the scale +40 us. k_scale stays separate.
//  - r7(old): MFMA-based DFT regressed (scattered stores). VALU DFT.
//  - r2(this session): >128 live VGPRs at launch_bounds(512,2) => scratch
//    spill, 110 us. Keep per-wave accum footprint + cap in sync.
// XCD locality: k_g3 block bid=f lands on XCD f%8 = the XCD whose k_dft
// blocks (bid&7 == f%8) wrote X_f -> staging reads are same-XCD L2 hits.
// ws layout: [0] float s3; [256] bufX bf16 [f][2][a][o] (21.4 MB).
// ---------------------------------------------------------------------------

// X[f][part][a*CH+o] = DFT_17x17(K[o][a])(w_f) * 2^-10.
// Thread owns p0..p0+7 (8 consecutive o, one a); kv in VGPRs across 5 freqs.
__global__ void k_dft(const float* __restrict__ K, bf16* __restrict__ X,
                      float* __restrict__ s3) {
    __shared__ float twc[17], tws[17];
    int bid = blockIdx.x;                 // 8 * 4 * 18 = 576
    int xcd = bid & 7;
    int r = bid >> 3;
    int g = r / 18, chunk = r % 18;
    int t = threadIdx.x;
    if (bid == 0 && t == 0) *s3 = 0.0f;   // stream-ordered: done before k_g3
    if (t < 17) {
        float s, c;
        __sincosf(-W17 * (float)t, &s, &c);
        twc[t] = c; tws[t] = s;
    }
    int p0 = chunk * 2048 + t * 8;        // p = a*CH + o; 8-run stays in one a-row
    int a = p0 / CH, o0 = p0 % CH;
    float kv[8][9];
#pragma unroll
    for (int j = 0; j < 8; ++j) {
        const float* src = K + ((size_t)(o0 + j) * CH + a) * 9;
#pragma unroll
        for (int i = 0; i < 9; ++i) kv[j][i] = src[i];
    }
    __syncthreads();
#pragma unroll
    for (int u = 0; u < 5; ++u) {
        int f = xcd + 8 * (g * 5 + u);    // f % 8 == xcd; covers f < 160
        if (f >= NF) continue;            // uniform per block
        int fy, fx;
        if (f < 9) { fy = 0; fx = f; }
        else { int uu = f - 9; fy = 1 + uu / 17; fx = uu % 17; }
        float pyr = twc[fy], pyi = tws[fy];
        float pxr = twc[fx], pxi = tws[fx];
        int fx2 = 2 * fx; if (fx2 >= 17) fx2 -= 17;
        int fy2 = 2 * fy; if (fy2 >= 17) fy2 -= 17;
        float px2r = twc[fx2], px2i = tws[fx2];
        float py2r = twc[fy2], py2i = tws[fy2];
        bf16x8 vr, vi;
#pragma unroll
        for (int j = 0; j < 8; ++j) {
            // row sums s_y = kv[y][0] + kv[y][1]*px + kv[y][2]*px^2  (kv real)
            float s0r = kv[j][0] + kv[j][1] * pxr + kv[j][2] * px2r, s0i = kv[j][1] * pxi + kv[j][2] * px2i;
            float s1r = kv[j][3] + kv[j][4] * pxr + kv[j][5] * px2r, s1i = kv[j][4] * pxi + kv[j][5] * px2i;
            float s2r = kv[j][6] + kv[j][7] * pxr + kv[j][8] * px2r, s2i = kv[j][7] * pxi + kv[j][8] * px2i;
            float ar = s0r + pyr * s1r - pyi * s1i + py2r * s2r - py2i * s2i;
            float ai = s0i + pyr * s1i + pyi * s1r + py2r * s2i + py2i * s2r;
            vr[j] = (bf16)(ar * XSCALE);
            vi[j] = (bf16)(ai * XSCALE);
        }
        size_t base = (size_t)f * FSTRIDE + p0;
        *(i32x4*)(X + base)       = __builtin_bit_cast(i32x4, vr);
        *(i32x4*)(X + base + MAT) = __builtin_bit_cast(i32x4, vi);
    }
}

// ---------------------------------------------------------------------------
// k_g3: per-frequency fused triple gram. One block = one freq, 512 threads.
// LDS: Re slab [192][200] bf16 + Im slab [192][200] = 153600 B.
// Uniform 16 tiles of 48x48: wave w owns rows rb=(w>>1)*48, cols
// (w&1)*96 .. +95 (two 48x48 tiles sharing A-row frags). Round: MFMA from
// LDS -> barrier -> accum->bf16 row-major write-back -> barrier.
// ---------------------------------------------------------------------------
#define S3S 200                   // slab stride (bf16 elems); 400 B rows
#define SLAB3 (192 * S3S)         // 38400 elems per slab

__global__ __launch_bounds__(512, 1) void k_g3(const bf16* __restrict__ X,
                                               float* __restrict__ s3) {
    __shared__ __align__(16) bf16 lds[2 * SLAB3];   // Re, Im: 153600 B
    __shared__ float red[8];
    int f = blockIdx.x;                 // 145 blocks; bid%8 == f%8 (writer XCD)
    const bf16* Xf = X + (size_t)f * FSTRIDE;
    int tid = threadIdx.x;
    int lane = tid & 63, w = tid >> 6;
    int ml = lane & 15, kq = (lane >> 4) * 8;
    int rb  = (w >> 1) * 48;            // row band
    int cb1 = (w & 1) * 96;             // col half, tile 1
    int cb2 = cb1 + 48;                 // col half, tile 2

    // ---- stage X_f -> LDS (fully unrolled, compile-time v[] indices) ----
    {
        i32x4 v[18];
#pragma unroll
        for (int s = 0; s < 2; ++s)
#pragma unroll
            for (int j = 0; j < 9; ++j) {
                int c = j * 512 + tid;              // 4608 16-B chunks per slab
                int rr = c / 24, cc = c % 24;
                v[s * 9 + j] = *(const i32x4*)(Xf + (s ? MAT : 0) + rr * CH + cc * 8);
            }
#pragma unroll
        for (int s = 0; s < 2; ++s)
#pragma unroll
            for (int j = 0; j < 9; ++j) {
                int c = j * 512 + tid;
                int rr = c / 24, cc = c % 24;
                *(i32x4*)&lds[s * SLAB3 + rr * S3S + cc * 8] = v[s * 9 + j];
            }
    }
    __syncthreads();

    f32x4 cr1[3][3], ci1[3][3], cr2[3][3], ci2[3][3];
#pragma unroll 1
    for (int round = 0; round < 3; ++round) {
#pragma unroll
        for (int i = 0; i < 3; ++i)
#pragma unroll
            for (int j = 0; j < 3; ++j) {
                cr1[i][j] = f32x4{0.f, 0.f, 0.f, 0.f};
                ci1[i][j] = f32x4{0.f, 0.f, 0.f, 0.f};
                cr2[i][j] = f32x4{0.f, 0.f, 0.f, 0.f};
                ci2[i][j] = f32x4{0.f, 0.f, 0.f, 0.f};
            }
#pragma unroll
        for (int ks = 0; ks < 192; ks += 32) {
            int ko = ks + kq;
            bf16x8 ar[3], ai[3], nai[3];
#pragma unroll
            for (int mt = 0; mt < 3; ++mt) {
                ar[mt] = *(const bf16x8*)&lds[(rb + mt * 16 + ml) * S3S + ko];
                ai[mt] = *(const bf16x8*)&lds[SLAB3 + (rb + mt * 16 + ml) * S3S + ko];
                i32x4 u = __builtin_bit_cast(i32x4, ai[mt]);
                u ^= 0x80008000;                    // negate 8 bf16
                nai[mt] = __builtin_bit_cast(bf16x8, u);
            }
#pragma unroll
            for (int nt = 0; nt < 3; ++nt) {
                bf16x8 br = *(const bf16x8*)&lds[(cb1 + nt * 16 + ml) * S3S + ko];
                bf16x8 bi = *(const bf16x8*)&lds[SLAB3 + (cb1 + nt * 16 + ml) * S3S + ko];
#pragma unroll
                for (int mt = 0; mt < 3; ++mt) {
                    cr1[mt][nt] = __builtin_amdgcn_mfma_f32_16x16x32_bf16(ar[mt],  br, cr1[mt][nt], 0, 0, 0);
                    cr1[mt][nt] = __builtin_amdgcn_mfma_f32_16x16x32_bf16(ai[mt],  bi, cr1[mt][nt], 0, 0, 0);
                    ci1[mt][nt] = __builtin_amdgcn_mfma_f32_16x16x32_bf16(ar[mt],  bi, ci1[mt][nt], 0, 0, 0);
                    ci1[mt][nt] = __builtin_amdgcn_mfma_f32_16x16x32_bf16(nai[mt], br, ci1[mt][nt], 0, 0, 0);
                }
                bf16x8 br2 = *(const bf16x8*)&lds[(cb2 + nt * 16 + ml) * S3S + ko];
                bf16x8 bi2 = *(const bf16x8*)&lds[SLAB3 + (cb2 + nt * 16 + ml) * S3S + ko];
#pragma unroll
                for (int mt = 0; mt < 3; ++mt) {
                    cr2[mt][nt] = __builtin_amdgcn_mfma_f32_16x16x32_bf16(ar[mt],  br2, cr2[mt][nt], 0, 0, 0);
                    cr2[mt][nt] = __builtin_amdgcn_mfma_f32_16x16x32_bf16(ai[mt],  bi2, cr2[mt][nt], 0, 0, 0);
                    ci2[mt][nt] = __builtin_amdgcn_mfma_f32_16x16x32_bf16(ar[mt],  bi2, ci2[mt][nt], 0, 0, 0);
                    ci2[mt][nt] = __builtin_amdgcn_mfma_f32_16x16x32_bf16(nai[mt], br2, ci2[mt][nt], 0, 0, 0);
                }
            }
        }
        if (round < 2) {
            __syncthreads();                        // all LDS reads done
            int lr = (lane >> 4) * 4;
#pragma unroll
            for (int mt = 0; mt < 3; ++mt)
#pragma unroll
                for (int nt = 0; nt < 3; ++nt)
#pragma unroll
                    for (int rr = 0; rr < 4; ++rr) {
                        int row = rb + mt * 16 + lr + rr;
                        int c1 = cb1 + nt * 16 + ml;
                        int c2 = cb2 + nt * 16 + ml;
                        lds[row * S3S + c1]         = (bf16)cr1[mt][nt][rr];
                        lds[SLAB3 + row * S3S + c1] = (bf16)ci1[mt][nt][rr];
                        lds[row * S3S + c2]         = (bf16)cr2[mt][nt][rr];
                        lds[SLAB3 + row * S3S + c2] = (bf16)ci2[mt][nt][rr];
                    }
            __syncthreads();                        // writes visible to round+1
        }
    }

    // ---- Frobenius norm of round-3 accums (full matrix, weight 1/tile) ----
    float loc = 0.f;
#pragma unroll
    for (int mt = 0; mt < 3; ++mt)
#pragma unroll
        for (int nt = 0; nt < 3; ++nt)
#pragma unroll
            for (int rr = 0; rr < 4; ++rr) {
                loc += cr1[mt][nt][rr] * cr1[mt][nt][rr] + ci1[mt][nt][rr] * ci1[mt][nt][rr];
                loc += cr2[mt][nt][rr] * cr2[mt][nt][rr] + ci2[mt][nt][rr] * ci2[mt][nt][rr];
            }
#pragma unroll
    for (int off = 32; off > 0; off >>= 1) loc += __shfl_down(loc, off, 64);
    if (lane == 0) red[w] = loc;
    __syncthreads();
    if (tid == 0) {
        float base = (f == 0) ? 1.0f : 2.0f;        // conj-pair weight over freqs
        atomicAdd(s3, base * (red[0] + red[1] + red[2] + red[3] +
                              red[4] + red[5] + red[6] + red[7]));
    }
}

// sigma = 1024 * (s3/289)^(1/16);  out = K / sigma
__global__ void k_scale(const float* __restrict__ K, float* __restrict__ out,
                        const float* __restrict__ s3) {
    float sig = 1024.0f * exp2f(log2f((*s3) * (1.0f / 289.0f)) * 0.0625f);
    float inv = 1.0f / sig;
    int i = (blockIdx.x * 256 + threadIdx.x) * 4;   // 324 blocks exact
    f32x4 v = *(const f32x4*)(K + i);
    v *= inv;
    *(f32x4*)(out + i) = v;
}

extern "C" void kernel_launch(void* const* d_in, const int* in_sizes, int n_in,
                              void* d_out, int out_size, void* d_ws, size_t ws_size,
                              hipStream_t stream) {
    const float* K = (const float*)d_in[0];
    float* out = (float*)d_out;
    char* ws = (char*)d_ws;
    float* s3 = (float*)ws;
    bf16* bufX = (bf16*)(ws + 256);

    k_dft<<<8 * 4 * 18, 256, 0, stream>>>(K, bufX, s3);       // X (21.4 MB)
    k_g3<<<NF, 512, 0, stream>>>(bufX, s3);                   // 3 gram rounds in LDS
    k_scale<<<NELEM / 1024, 256, 0, stream>>>(K, out, s3);    // out = K/sigma
}

// Round 4
// 133.533 us; speedup vs baseline: 1.3362x; 1.2922x over previous
//
#include <hip/hip_runtime.h>
#include <hip/hip_bf16.h>

typedef __bf16 bf16;
typedef __attribute__((ext_vector_type(8))) __bf16 bf16x8;
typedef __attribute__((ext_vector_type(4))) float f32x4;
typedef __attribute__((ext_vector_type(4))) int i32x4;

#define CH 192
#define MAT (CH * CH)            // 36864
#define NF 145                   // canonical frequencies of 17x17 grid (conj symmetry)
#define FSTRIDE (2 * MAT)        // Re+Im per freq
#define NELEM (CH * CH * 9)      // 331776
#define XSCALE 9.765625e-4f      // 2^-10, exact; sigma = 1024*(s3/289)^(1/16)
#define W17 0.36959913571644626f // 2*pi/17

// ---------------------------------------------------------------------------
// sigma = ||G^3(K)||_F^(1/8) via 17x17 spectral sampling (exact Parseval).
// ROUND-9 CHANGE (spill fix, take 2): an 8-wave block caps at 256 regs/wave
// (2 waves/SIMD x 512-reg pool); the dual-tile wave needed ~270 -> spill was
// STRUCTURAL (launch_bounds can't help; r3 proved it: VGPR stuck at 128,
// WRITE_SIZE 53MB scratch). Fix: ONE 48x48 tile per wave, 16 waves (1024
// threads). Per-wave: 72 accum + 24 A-frag + 12 transient B + addr ~= 120
// <= 128 cap (4 waves/SIMD). Negation moved to B per-nt (ai*(-br) ==
// (-ai)*br bitwise; keeps transient 4 regs vs nai[3]=12). Occupancy
// 2 -> 4 waves/SIMD.
// Lessons pinned:
//  - r4(old): runtime trip counts spill v[] to scratch. Staging FULLY
//    UNROLLED with compile-time v[] indices.
//  - r6(old): spinner-block fusion of k_scale +40 us. Keep separate.
//  - r7(old): MFMA-based DFT regressed (scattered stores). VALU DFT.
//  - r2/r3(this session): wave reg budget = pool(512/SIMD)/(waves/SIMD).
//    8-wave block -> 256/wave; 16-wave block -> 128/wave. Size accum
//    footprint to the cap or scratch traffic eats 100 us.
//  - The harness workspace fill (~44 us, 268 MB) is INSIDE the timed
//    window: floor = 44 + kernels. Don't chase below that with ws-dependent
//    tricks.
// XCD locality: k_g3 block bid=f lands on XCD f%8 = the XCD whose k_dft
// blocks (bid&7 == f%8) wrote X_f -> staging reads are same-XCD L2 hits.
// ws layout: [0] float s3; [256] bufX bf16 [f][2][a][o] (21.4 MB).
// ---------------------------------------------------------------------------

// X[f][part][a*CH+o] = DFT_17x17(K[o][a])(w_f) * 2^-10.
// Thread owns p0..p0+7 (8 consecutive o, one a); kv in VGPRs across 5 freqs.
__global__ void k_dft(const float* __restrict__ K, bf16* __restrict__ X,
                      float* __restrict__ s3) {
    __shared__ float twc[17], tws[17];
    int bid = blockIdx.x;                 // 8 * 4 * 18 = 576
    int xcd = bid & 7;
    int r = bid >> 3;
    int g = r / 18, chunk = r % 18;
    int t = threadIdx.x;
    if (bid == 0 && t == 0) *s3 = 0.0f;   // stream-ordered: done before k_g3
    if (t < 17) {
        float s, c;
        __sincosf(-W17 * (float)t, &s, &c);
        twc[t] = c; tws[t] = s;
    }
    int p0 = chunk * 2048 + t * 8;        // p = a*CH + o; 8-run stays in one a-row
    int a = p0 / CH, o0 = p0 % CH;
    float kv[8][9];
#pragma unroll
    for (int j = 0; j < 8; ++j) {
        const float* src = K + ((size_t)(o0 + j) * CH + a) * 9;
#pragma unroll
        for (int i = 0; i < 9; ++i) kv[j][i] = src[i];
    }
    __syncthreads();
#pragma unroll
    for (int u = 0; u < 5; ++u) {
        int f = xcd + 8 * (g * 5 + u);    // f % 8 == xcd; covers f < 160
        if (f >= NF) continue;            // uniform per block
        int fy, fx;
        if (f < 9) { fy = 0; fx = f; }
        else { int uu = f - 9; fy = 1 + uu / 17; fx = uu % 17; }
        float pyr = twc[fy], pyi = tws[fy];
        float pxr = twc[fx], pxi = tws[fx];
        int fx2 = 2 * fx; if (fx2 >= 17) fx2 -= 17;
        int fy2 = 2 * fy; if (fy2 >= 17) fy2 -= 17;
        float px2r = twc[fx2], px2i = tws[fx2];
        float py2r = twc[fy2], py2i = tws[fy2];
        bf16x8 vr, vi;
#pragma unroll
        for (int j = 0; j < 8; ++j) {
            // row sums s_y = kv[y][0] + kv[y][1]*px + kv[y][2]*px^2  (kv real)
            float s0r = kv[j][0] + kv[j][1] * pxr + kv[j][2] * px2r, s0i = kv[j][1] * pxi + kv[j][2] * px2i;
            float s1r = kv[j][3] + kv[j][4] * pxr + kv[j][5] * px2r, s1i = kv[j][4] * pxi + kv[j][5] * px2i;
            float s2r = kv[j][6] + kv[j][7] * pxr + kv[j][8] * px2r, s2i = kv[j][7] * pxi + kv[j][8] * px2i;
            float ar = s0r + pyr * s1r - pyi * s1i + py2r * s2r - py2i * s2i;
            float ai = s0i + pyr * s1i + pyi * s1r + py2r * s2i + py2i * s2r;
            vr[j] = (bf16)(ar * XSCALE);
            vi[j] = (bf16)(ai * XSCALE);
        }
        size_t base = (size_t)f * FSTRIDE + p0;
        *(i32x4*)(X + base)       = __builtin_bit_cast(i32x4, vr);
        *(i32x4*)(X + base + MAT) = __builtin_bit_cast(i32x4, vi);
    }
}

// ---------------------------------------------------------------------------
// k_g3: per-frequency fused triple gram. One block = one freq, 1024 threads.
// LDS: Re slab [192][200] bf16 + Im slab [192][200] = 153600 B (1 block/CU).
// 16 waves, wave w owns ONE 48x48 tile: rows (w>>2)*48, cols (w&3)*48.
// Round: MFMA from LDS -> barrier -> accum->bf16 row-major write-back ->
// barrier. Final round: Frobenius norm of accums -> atomic.
// ---------------------------------------------------------------------------
#define S3S 200                   // slab stride (bf16 elems); 400 B rows
#define SLAB3 (192 * S3S)         // 38400 elems per slab

__global__ __launch_bounds__(1024, 1) void k_g3(const bf16* __restrict__ X,
                                                float* __restrict__ s3) {
    __shared__ __align__(16) bf16 lds[2 * SLAB3];   // Re, Im: 153600 B
    __shared__ float red[16];
    int f = blockIdx.x;                 // 145 blocks; bid%8 == f%8 (writer XCD)
    const bf16* Xf = X + (size_t)f * FSTRIDE;
    int tid = threadIdx.x;
    int lane = tid & 63, w = tid >> 6;
    int ml = lane & 15, kq = (lane >> 4) * 8;
    int rb = (w >> 2) * 48;             // row band
    int cb = (w & 3) * 48;              // col band

    // ---- stage X_f -> LDS (fully unrolled, compile-time v[] indices) ----
    {
        i32x4 v[9];                     // 9216 16-B chunks over 1024 threads
#pragma unroll
        for (int j = 0; j < 9; ++j) {
            int c = j * 1024 + tid;
            int s = c / 4608, ci = c % 4608;
            int rr = ci / 24, cc = ci % 24;
            v[j] = *(const i32x4*)(Xf + (size_t)s * MAT + rr * CH + cc * 8);
        }
#pragma unroll
        for (int j = 0; j < 9; ++j) {
            int c = j * 1024 + tid;
            int s = c / 4608, ci = c % 4608;
            int rr = ci / 24, cc = ci % 24;
            *(i32x4*)&lds[s * SLAB3 + rr * S3S + cc * 8] = v[j];
        }
    }
    __syncthreads();

    f32x4 cr[3][3], ci[3][3];
#pragma unroll 1
    for (int round = 0; round < 3; ++round) {
#pragma unroll
        for (int i = 0; i < 3; ++i)
#pragma unroll
            for (int j = 0; j < 3; ++j) {
                cr[i][j] = f32x4{0.f, 0.f, 0.f, 0.f};
                ci[i][j] = f32x4{0.f, 0.f, 0.f, 0.f};
            }
#pragma unroll
        for (int ks = 0; ks < 192; ks += 32) {
            int ko = ks + kq;
            bf16x8 ar[3], ai[3];
#pragma unroll
            for (int mt = 0; mt < 3; ++mt) {
                ar[mt] = *(const bf16x8*)&lds[(rb + mt * 16 + ml) * S3S + ko];
                ai[mt] = *(const bf16x8*)&lds[SLAB3 + (rb + mt * 16 + ml) * S3S + ko];
            }
#pragma unroll
            for (int nt = 0; nt < 3; ++nt) {
                bf16x8 br = *(const bf16x8*)&lds[(cb + nt * 16 + ml) * S3S + ko];
                bf16x8 bi = *(const bf16x8*)&lds[SLAB3 + (cb + nt * 16 + ml) * S3S + ko];
                i32x4 u = __builtin_bit_cast(i32x4, br);
                u ^= 0x80008000;                    // nbr = -br (8 bf16)
                bf16x8 nbr = __builtin_bit_cast(bf16x8, u);
#pragma unroll
                for (int mt = 0; mt < 3; ++mt) {
                    // cr += ar*br + ai*bi ; ci += ar*bi + ai*(-br)
                    cr[mt][nt] = __builtin_amdgcn_mfma_f32_16x16x32_bf16(ar[mt], br,  cr[mt][nt], 0, 0, 0);
                    cr[mt][nt] = __builtin_amdgcn_mfma_f32_16x16x32_bf16(ai[mt], bi,  cr[mt][nt], 0, 0, 0);
                    ci[mt][nt] = __builtin_amdgcn_mfma_f32_16x16x32_bf16(ar[mt], bi,  ci[mt][nt], 0, 0, 0);
                    ci[mt][nt] = __builtin_amdgcn_mfma_f32_16x16x32_bf16(ai[mt], nbr, ci[mt][nt], 0, 0, 0);
                }
            }
        }
        if (round < 2) {
            __syncthreads();                        // all LDS reads done
            int lr = (lane >> 4) * 4;
#pragma unroll
            for (int mt = 0; mt < 3; ++mt)
#pragma unroll
                for (int nt = 0; nt < 3; ++nt)
#pragma unroll
                    for (int rr = 0; rr < 4; ++rr) {
                        int row = rb + mt * 16 + lr + rr;
                        int cc = cb + nt * 16 + ml;
                        lds[row * S3S + cc]         = (bf16)cr[mt][nt][rr];
                        lds[SLAB3 + row * S3S + cc] = (bf16)ci[mt][nt][rr];
                    }
            __syncthreads();                        // writes visible to round+1
        }
    }

    // ---- Frobenius norm of round-3 accums (full matrix, weight 1/tile) ----
    float loc = 0.f;
#pragma unroll
    for (int mt = 0; mt < 3; ++mt)
#pragma unroll
        for (int nt = 0; nt < 3; ++nt)
#pragma unroll
            for (int rr = 0; rr < 4; ++rr)
                loc += cr[mt][nt][rr] * cr[mt][nt][rr] + ci[mt][nt][rr] * ci[mt][nt][rr];
#pragma unroll
    for (int off = 32; off > 0; off >>= 1) loc += __shfl_down(loc, off, 64);
    if (lane == 0) red[w] = loc;
    __syncthreads();
    if (tid == 0) {
        float base = (f == 0) ? 1.0f : 2.0f;        // conj-pair weight over freqs
        float acc = 0.f;
#pragma unroll
        for (int i = 0; i < 16; ++i) acc += red[i];
        atomicAdd(s3, base * acc);
    }
}

// sigma = 1024 * (s3/289)^(1/16);  out = K / sigma
__global__ void k_scale(const float* __restrict__ K, float* __restrict__ out,
                        const float* __restrict__ s3) {
    float sig = 1024.0f * exp2f(log2f((*s3) * (1.0f / 289.0f)) * 0.0625f);
    float inv = 1.0f / sig;
    int i = (blockIdx.x * 256 + threadIdx.x) * 4;   // 324 blocks exact
    f32x4 v = *(const f32x4*)(K + i);
    v *= inv;
    *(f32x4*)(out + i) = v;
}

extern "C" void kernel_launch(void* const* d_in, const int* in_sizes, int n_in,
                              void* d_out, int out_size, void* d_ws, size_t ws_size,
                              hipStream_t stream) {
    const float* K = (const float*)d_in[0];
    float* out = (float*)d_out;
    char* ws = (char*)d_ws;
    float* s3 = (float*)ws;
    bf16* bufX = (bf16*)(ws + 256);

    k_dft<<<8 * 4 * 18, 256, 0, stream>>>(K, bufX, s3);       // X (21.4 MB)
    k_g3<<<NF, 1024, 0, stream>>>(bufX, s3);                  // 3 gram rounds in LDS
    k_scale<<<NELEM / 1024, 256, 0, stream>>>(K, out, s3);    // out = K/sigma
}

// Round 5
// 111.427 us; speedup vs baseline: 1.6013x; 1.1984x over previous
//
#include <hip/hip_runtime.h>
#include <hip/hip_bf16.h>

typedef __bf16 bf16;
typedef __attribute__((ext_vector_type(8))) __bf16 bf16x8;
typedef __attribute__((ext_vector_type(4))) float f32x4;
typedef __attribute__((ext_vector_type(4))) int i32x4;

#define CH 192
#define MAT (CH * CH)            // 36864
#define NF 145                   // canonical frequencies of 17x17 grid (conj symmetry)
#define FSTRIDE (2 * MAT)        // Re+Im per freq
#define NELEM (CH * CH * 9)      // 331776
#define XSCALE 9.765625e-4f      // 2^-10, exact; sigma = 1024*(s3/289)^(1/16)
#define W17 0.36959913571644626f // 2*pi/17

// ---------------------------------------------------------------------------
// sigma = ||G^3(K)||_F^(1/8) via 17x17 spectral sampling (exact Parseval).
// ROUND-10 CHANGE (spill fix, take 3): r4 showed VGPR_Count=64 + 44MB scratch
// both ways -> the allocator chased 8 waves/EU (64-reg budget) and spilled the
// 72 accumulator regs. launch_bounds min-arg can't forbid that. Fixes:
//  - amdgpu_waves_per_eu(4,4): EXACTLY 4 waves/EU -> budget 512/4 = 128.
//  - global_load_lds width-16 staging: no VGPR round-trip (frees v[9]=36 regs).
//    Requires LINEAR LDS rows -> stride 192 (384 B), bank-fixed by XOR chunk
//    swizzle c' = (c&~7)|((c&7)^(r&7)) applied BOTH sides (rule #21): k_dft
//    pre-swizzles its global stores, k_g3 stages linearly and reads/writes
//    back through the same swizzle. LDS 153.6 -> 144 KB.
//  - Live set: 72 accum + 24 A-frag + ~12 B transient + addr ~= 120 <= 128.
// Lessons pinned:
//  - wave reg budget = 512/(waves per SIMD). 16-wave block -> 128/wave;
//    8-wave -> 256. Accum footprint must fit or scratch eats 100 us.
//  - compiler will VOLUNTARILY drop to 64 regs (8 waves/EU) and spill;
//    only amdgpu_waves_per_eu(max) pins it.
//  - staging FULLY UNROLLED, compile-time indices (r4-old).
//  - k_scale fusion via spinner regressed (r6-old). Keep separate dispatch.
//  - harness ws fill (~44 us) is inside the timed window: floor = 44 + work.
// XCD locality: k_g3 block bid=f lands on XCD f%8 = the XCD whose k_dft
// blocks (bid&7 == f%8) wrote X_f -> staging reads are same-XCD L2 hits.
// ws layout: [0] float s3; [256] bufX bf16 [f][2][a][swizzled o] (21.4 MB).
// ---------------------------------------------------------------------------

__device__ __forceinline__ int swz8(int c, int r) {
    return (c & ~7) | ((c & 7) ^ (r & 7));       // 16-B chunk XOR swizzle
}

// X[f][part][a][swz cols] = DFT_17x17(K[o][a])(w_f) * 2^-10, PRE-SWIZZLED so
// k_g3's global_load_lds staging is a linear copy while LDS reads stay
// bank-balanced. Thread owns 8 consecutive o (one a); kv in VGPRs, 5 freqs.
__global__ void k_dft(const float* __restrict__ K, bf16* __restrict__ X,
                      float* __restrict__ s3) {
    __shared__ float twc[17], tws[17];
    int bid = blockIdx.x;                 // 8 * 4 * 18 = 576
    int xcd = bid & 7;
    int r = bid >> 3;
    int g = r / 18, chunk = r % 18;
    int t = threadIdx.x;
    if (bid == 0 && t == 0) *s3 = 0.0f;   // stream-ordered: done before k_g3
    if (t < 17) {
        float s, c;
        __sincosf(-W17 * (float)t, &s, &c);
        twc[t] = c; tws[t] = s;
    }
    int p0 = chunk * 2048 + t * 8;        // p = a*CH + o; 8-run stays in one a-row
    int a = p0 / CH, o0 = p0 % CH;
    float kv[8][9];
#pragma unroll
    for (int j = 0; j < 8; ++j) {
        const float* src = K + ((size_t)(o0 + j) * CH + a) * 9;
#pragma unroll
        for (int i = 0; i < 9; ++i) kv[j][i] = src[i];
    }
    // swizzled store position (chunk c0 of row a)
    int sc = swz8(o0 >> 3, a);
    size_t sbase = (size_t)a * CH + sc * 8;
    __syncthreads();
#pragma unroll
    for (int u = 0; u < 5; ++u) {
        int f = xcd + 8 * (g * 5 + u);    // f % 8 == xcd; covers f < 160
        if (f >= NF) continue;            // uniform per block
        int fy, fx;
        if (f < 9) { fy = 0; fx = f; }
        else { int uu = f - 9; fy = 1 + uu / 17; fx = uu % 17; }
        float pyr = twc[fy], pyi = tws[fy];
        float pxr = twc[fx], pxi = tws[fx];
        int fx2 = 2 * fx; if (fx2 >= 17) fx2 -= 17;
        int fy2 = 2 * fy; if (fy2 >= 17) fy2 -= 17;
        float px2r = twc[fx2], px2i = tws[fx2];
        float py2r = twc[fy2], py2i = tws[fy2];
        bf16x8 vr, vi;
#pragma unroll
        for (int j = 0; j < 8; ++j) {
            // row sums s_y = kv[y][0] + kv[y][1]*px + kv[y][2]*px^2  (kv real)
            float s0r = kv[j][0] + kv[j][1] * pxr + kv[j][2] * px2r, s0i = kv[j][1] * pxi + kv[j][2] * px2i;
            float s1r = kv[j][3] + kv[j][4] * pxr + kv[j][5] * px2r, s1i = kv[j][4] * pxi + kv[j][5] * px2i;
            float s2r = kv[j][6] + kv[j][7] * pxr + kv[j][8] * px2r, s2i = kv[j][7] * pxi + kv[j][8] * px2i;
            float ar = s0r + pyr * s1r - pyi * s1i + py2r * s2r - py2i * s2i;
            float ai = s0i + pyr * s1i + pyi * s1r + py2r * s2i + py2i * s2r;
            vr[j] = (bf16)(ar * XSCALE);
            vi[j] = (bf16)(ai * XSCALE);
        }
        size_t base = (size_t)f * FSTRIDE + sbase;
        *(i32x4*)(X + base)       = __builtin_bit_cast(i32x4, vr);
        *(i32x4*)(X + base + MAT) = __builtin_bit_cast(i32x4, vi);
    }
}

// ---------------------------------------------------------------------------
// k_g3: per-frequency fused triple gram. One block = one freq, 1024 threads.
// LDS: Re slab [192][192] + Im slab (XOR-swizzled chunks) = 147456 B.
// 16 waves, wave w owns ONE 48x48 tile: rows (w>>2)*48, cols (w&3)*48.
// Round: MFMA from LDS -> barrier -> accum->bf16 swizzled write-back ->
// barrier. Final round: Frobenius norm of accums -> atomic.
// ---------------------------------------------------------------------------
__global__ __launch_bounds__(1024, 4)
__attribute__((amdgpu_waves_per_eu(4, 4)))
void k_g3(const bf16* __restrict__ X, float* __restrict__ s3) {
    __shared__ __align__(16) bf16 lds[2 * MAT];   // 147456 B
    __shared__ float red[16];
    int f = blockIdx.x;                 // 145 blocks; bid%8 == f%8 (writer XCD)
    const bf16* Xf = X + (size_t)f * FSTRIDE;
    int tid = threadIdx.x;
    int lane = tid & 63, w = tid >> 6;
    int ml = lane & 15, kqc = lane >> 4;
    int rb = (w >> 2) * 48;             // row band
    int cb = (w & 3) * 48;              // col band

    // ---- stage X_f -> LDS: linear 147456-B copy, direct-to-LDS 16-B ----
    {
        const char* gs = (const char*)Xf;
        char* lb = (char*)lds;
#pragma unroll
        for (int j = 0; j < 9; ++j) {
            __builtin_amdgcn_global_load_lds(
                (const __attribute__((address_space(1))) void*)(gs + (j * 1024 + tid) * 16),
                (__attribute__((address_space(3))) void*)(lb + (j * 1024 + (tid & ~63)) * 16),
                16, 0, 0);
        }
        asm volatile("s_waitcnt vmcnt(0)" ::: "memory");
    }
    __syncthreads();

    // per-thread frag row constants
    int arow[3], abit[3], brow[3], bbit[3];
#pragma unroll
    for (int i = 0; i < 3; ++i) {
        int ra = rb + i * 16 + ml;
        arow[i] = ra * CH; abit[i] = ra & 7;
        int rc = cb + i * 16 + ml;
        brow[i] = rc * CH; bbit[i] = rc & 7;
    }

    f32x4 cr[3][3], ci[3][3];
#pragma unroll 1
    for (int round = 0; round < 3; ++round) {
#pragma unroll
        for (int i = 0; i < 3; ++i)
#pragma unroll
            for (int j = 0; j < 3; ++j) {
                cr[i][j] = f32x4{0.f, 0.f, 0.f, 0.f};
                ci[i][j] = f32x4{0.f, 0.f, 0.f, 0.f};
            }
#pragma unroll
        for (int ks8 = 0; ks8 < 24; ks8 += 4) {     // K step 32 = 4 chunks
            int c0 = ks8 + kqc;
            bf16x8 ar[3], ai[3];
#pragma unroll
            for (int mt = 0; mt < 3; ++mt) {
                int e = arow[mt] + swz8(c0, abit[mt]) * 8;
                ar[mt] = *(const bf16x8*)&lds[e];
                ai[mt] = *(const bf16x8*)&lds[MAT + e];
            }
#pragma unroll
            for (int nt = 0; nt < 3; ++nt) {
                int e = brow[nt] + swz8(c0, bbit[nt]) * 8;
                bf16x8 br = *(const bf16x8*)&lds[e];
                bf16x8 bi = *(const bf16x8*)&lds[MAT + e];
                i32x4 u = __builtin_bit_cast(i32x4, br);
                u ^= 0x80008000;                    // nbr = -br (8 bf16)
                bf16x8 nbr = __builtin_bit_cast(bf16x8, u);
#pragma unroll
                for (int mt = 0; mt < 3; ++mt) {
                    // cr += ar*br + ai*bi ; ci += ar*bi + ai*(-br)
                    cr[mt][nt] = __builtin_amdgcn_mfma_f32_16x16x32_bf16(ar[mt], br,  cr[mt][nt], 0, 0, 0);
                    cr[mt][nt] = __builtin_amdgcn_mfma_f32_16x16x32_bf16(ai[mt], bi,  cr[mt][nt], 0, 0, 0);
                    ci[mt][nt] = __builtin_amdgcn_mfma_f32_16x16x32_bf16(ar[mt], bi,  ci[mt][nt], 0, 0, 0);
                    ci[mt][nt] = __builtin_amdgcn_mfma_f32_16x16x32_bf16(ai[mt], nbr, ci[mt][nt], 0, 0, 0);
                }
            }
        }
        if (round < 2) {
            __syncthreads();                        // all LDS reads done
            int lr = kqc * 4;
#pragma unroll
            for (int mt = 0; mt < 3; ++mt)
#pragma unroll
                for (int nt = 0; nt < 3; ++nt)
#pragma unroll
                    for (int rr = 0; rr < 4; ++rr) {
                        int row = rb + mt * 16 + lr + rr;
                        int col = cb + nt * 16 + ml;
                        int e = row * CH + swz8(col >> 3, row) * 8 + (col & 7);
                        lds[e]       = (bf16)cr[mt][nt][rr];
                        lds[MAT + e] = (bf16)ci[mt][nt][rr];
                    }
            __syncthreads();                        // writes visible to round+1
        }
    }

    // ---- Frobenius norm of round-3 accums (full matrix, weight 1/tile) ----
    float loc = 0.f;
#pragma unroll
    for (int mt = 0; mt < 3; ++mt)
#pragma unroll
        for (int nt = 0; nt < 3; ++nt)
#pragma unroll
            for (int rr = 0; rr < 4; ++rr)
                loc += cr[mt][nt][rr] * cr[mt][nt][rr] + ci[mt][nt][rr] * ci[mt][nt][rr];
#pragma unroll
    for (int off = 32; off > 0; off >>= 1) loc += __shfl_down(loc, off, 64);
    if (lane == 0) red[w] = loc;
    __syncthreads();
    if (tid == 0) {
        float base = (f == 0) ? 1.0f : 2.0f;        // conj-pair weight over freqs
        float acc = 0.f;
#pragma unroll
        for (int i = 0; i < 16; ++i) acc += red[i];
        atomicAdd(s3, base * acc);
    }
}

// sigma = 1024 * (s3/289)^(1/16);  out = K / sigma
__global__ void k_scale(const float* __restrict__ K, float* __restrict__ out,
                        const float* __restrict__ s3) {
    float sig = 1024.0f * exp2f(log2f((*s3) * (1.0f / 289.0f)) * 0.0625f);
    float inv = 1.0f / sig;
    int i = (blockIdx.x * 256 + threadIdx.x) * 4;   // 324 blocks exact
    f32x4 v = *(const f32x4*)(K + i);
    v *= inv;
    *(f32x4*)(out + i) = v;
}

extern "C" void kernel_launch(void* const* d_in, const int* in_sizes, int n_in,
                              void* d_out, int out_size, void* d_ws, size_t ws_size,
                              hipStream_t stream) {
    const float* K = (const float*)d_in[0];
    float* out = (float*)d_out;
    char* ws = (char*)d_ws;
    float* s3 = (float*)ws;
    bf16* bufX = (bf16*)(ws + 256);

    k_dft<<<8 * 4 * 18, 256, 0, stream>>>(K, bufX, s3);       // X (21.4 MB, swizzled)
    k_g3<<<NF, 1024, 0, stream>>>(bufX, s3);                  // 3 gram rounds in LDS
    k_scale<<<NELEM / 1024, 256, 0, stream>>>(K, out, s3);    // out = K/sigma
}